// Round 12
// baseline (69.420 us; speedup 1.0000x reference)
//
#include <hip/hip_runtime.h>
#include <math.h>

#define INV_2PI_D 0.15915494309189535

// w = exp(2*pi*i*rev): hardware v_sin/v_cos take REVOLUTIONS.
// Twiddle revs are -k/2^m -- exactly representable, no range reduction.
__device__ __forceinline__ void wrev(float rev, float& c, float& s) {
    s = __builtin_amdgcn_sinf(rev);
    c = __builtin_amdgcn_cosf(rev);
}

// Cross-lane exchange lane <-> lane^S. Dependency is explicit SSA (return
// value) -> no compiler-invisible memory hazard, no drains.
// S=1,2: DPP quad_perm (VALU). S=8: DPP row_ror:8 == xor8 within row-16
// (VALU). S=4,16: ds_swizzle BitMode xor. S=32: shfl across halves.
template<int S>
__device__ __forceinline__ float xshfl(float x) {
    if constexpr (S == 1)
        return __int_as_float(__builtin_amdgcn_mov_dpp(__float_as_int(x), 0xB1, 0xF, 0xF, true));
    else if constexpr (S == 2)
        return __int_as_float(__builtin_amdgcn_mov_dpp(__float_as_int(x), 0x4E, 0xF, 0xF, true));
    else if constexpr (S == 8)
        return __int_as_float(__builtin_amdgcn_mov_dpp(__float_as_int(x), 0x128, 0xF, 0xF, true));
    else if constexpr (S == 4)
        return __int_as_float(__builtin_amdgcn_ds_swizzle(__float_as_int(x), 0x101F));
    else if constexpr (S == 16)
        return __int_as_float(__builtin_amdgcn_ds_swizzle(__float_as_int(x), 0x401F));
    else
        return __shfl_xor(x, 32, 64);
}

// Cross-lane stage S: gather ALL partners first (32 independent exchange ops
// -> DS/DPP pipe can stream them back-to-back), then combine. k=lane&(S-1)
// same for both partners; upper lane: out = own + w*partner; lower:
// out = partner - w*own  (i.e. c1*own + c2*partner, lane-selected).
template<int S>
__device__ __forceinline__ void stage_x(float (&re)[16], float (&im)[16], int lane) {
    float pr[16], pi[16];
#pragma unroll
    for (int r = 0; r < 16; ++r) { pr[r] = xshfl<S>(re[r]); pi[r] = xshfl<S>(im[r]); }
    float wr, wi;
    wrev(-(float)(lane & (S - 1)) * (0.5f / (float)S), wr, wi);
    const bool up = (lane & S) == 0;
    const float c1r = up ? 1.0f : -wr;
    const float c1i = up ? 0.0f : -wi;
    const float c2r = up ? wr : 1.0f;
    const float c2i = up ? wi : 0.0f;
#pragma unroll
    for (int r = 0; r < 16; ++r) {
        const float a = re[r], b = im[r];
        re[r] = a * c1r - b * c1i + pr[r] * c2r - pi[r] * c2i;
        im[r] = a * c1i + b * c1r + pr[r] * c2i + pi[r] * c2r;
    }
}

// S=1: w=(1,0) -> out = partner + sgn*own.
__device__ __forceinline__ void stage_x1(float (&re)[16], float (&im)[16], int lane) {
    float pr[16], pi[16];
#pragma unroll
    for (int r = 0; r < 16; ++r) { pr[r] = xshfl<1>(re[r]); pi[r] = xshfl<1>(im[r]); }
    const float sgn = (lane & 1) ? -1.0f : 1.0f;
#pragma unroll
    for (int r = 0; r < 16; ++r) {
        re[r] = __fmaf_rn(sgn, re[r], pr[r]);
        im[r] = __fmaf_rn(sgn, im[r], pi[r]);
    }
}

__device__ __forceinline__ void bfly(float& ar, float& ai, float& br, float& bi,
                                     float wr, float wi) {
    const float tr = wr * br - wi * bi;
    const float ti = wr * bi + wi * br;
    br = ar - tr; bi = ai - ti;
    ar = ar + tr; ai = ai + ti;
}

// Register-local stage, span 64*M: pairs (r, r|M), k = 64*(r&(M-1))+lane.
template<int M>
__device__ __forceinline__ void stage_r(float (&re)[16], float (&im)[16], float lanef) {
    float cw[M], sw[M];
#pragma unroll
    for (int m = 0; m < M; ++m)
        wrev(-(64.0f * (float)m + lanef) * (1.0f / (128.0f * (float)M)), cw[m], sw[m]);
#pragma unroll
    for (int rl = 0; rl < 16; ++rl) {
        if (rl & M) continue;
        bfly(re[rl], im[rl], re[rl | M], im[rl | M], cw[rl & (M - 1)], sw[rl & (M - 1)]);
    }
}

// Element map: e = r*64 + lane. Bit-reversed load folded into the float4
// gather (rev6(lane) covers each 64B granule exactly once -> coalesced).
static constexpr int RM_[4][4] = {
    {0, 8, 4, 12}, {2, 10, 6, 14}, {1, 9, 5, 13}, {3, 11, 7, 15}};

__device__ __forceinline__ void load_row(
    const float* __restrict__ xre, const float* __restrict__ xim,
    size_t base, int rev6l, float (&re)[16], float (&im)[16])
{
    const float4* xr4 = reinterpret_cast<const float4*>(xre + base) + (rev6l << 2);
    const float4* xi4 = reinterpret_cast<const float4*>(xim + base) + (rev6l << 2);
#pragma unroll
    for (int q = 0; q < 4; ++q) {
        const float4 vr = xr4[q];
        const float4 vi = xi4[q];
        re[RM_[q][0]] = vr.x; re[RM_[q][1]] = vr.y; re[RM_[q][2]] = vr.z; re[RM_[q][3]] = vr.w;
        im[RM_[q][0]] = vi.x; im[RM_[q][1]] = vi.y; im[RM_[q][2]] = vi.z; im[RM_[q][3]] = vi.w;
    }
}

__device__ __forceinline__ void fft_compute(float (&re)[16], float (&im)[16],
                                            int lane, float lanef)
{
    stage_x1(re, im, lane);
    stage_x<2>(re, im, lane);
    stage_x<4>(re, im, lane);
    stage_x<8>(re, im, lane);
    stage_x<16>(re, im, lane);
    stage_x<32>(re, im, lane);
    stage_r<1>(re, im, lanef);
    stage_r<2>(re, im, lanef);
    stage_r<4>(re, im, lanef);
    stage_r<8>(re, im, lanef);
}

__device__ __forceinline__ void store_row(
    float* __restrict__ yre, float* __restrict__ yim,
    size_t base, int lane, float (&re)[16], float (&im)[16])
{
    float* yr = yre + base + lane;
    float* yi = yim + base + lane;
#pragma unroll
    for (int r = 0; r < 16; ++r) {
        yr[r << 6] = re[r];
        yi[r << 6] = im[r];
    }
}

// 4 rows per wave, software-pipelined: row i+1's loads are issued before
// row i's compute, so HBM latency hides under own-wave VALU/DS work.
// A/B register sets statically alternated (no runtime indexing).
__device__ void fft_wave(const float* __restrict__ xre, const float* __restrict__ xim,
                         float* __restrict__ yre, float* __restrict__ yim, int row0)
{
    const int lane = (int)(threadIdx.x & 63u);
    const float lanef = (float)lane;
    const int rev6l = (int)(__brev((unsigned)lane) >> 26);

    const size_t b0 = (size_t)row0 << 10;
    const size_t b1 = (size_t)(row0 + 1) << 10;
    const size_t b2 = (size_t)(row0 + 2) << 10;
    const size_t b3 = (size_t)(row0 + 3) << 10;

    float Ar[16], Ai[16], Br[16], Bi[16];

    load_row(xre, xim, b0, rev6l, Ar, Ai);
    load_row(xre, xim, b1, rev6l, Br, Bi);      // prefetch row 1
    fft_compute(Ar, Ai, lane, lanef);
    store_row(yre, yim, b0, lane, Ar, Ai);

    load_row(xre, xim, b2, rev6l, Ar, Ai);      // prefetch row 2
    fft_compute(Br, Bi, lane, lanef);
    store_row(yre, yim, b1, lane, Br, Bi);

    load_row(xre, xim, b3, rev6l, Br, Bi);      // prefetch row 3
    fft_compute(Ar, Ai, lane, lanef);
    store_row(yre, yim, b2, lane, Ar, Ai);

    fft_compute(Br, Bi, lane, lanef);
    store_row(yre, yim, b3, lane, Br, Bi);
}

// Z: table built in-block (4 f64 log/sqrt per thread -- trivial), then the
// float32-semantics phase/cos loop (matches reference rounding).
__device__ void z_eval(const float* __restrict__ tin, float* __restrict__ zout,
                       int zblock, int n, float* __restrict__ buf)
{
    float* slog = buf;
    float* srsq = buf + 1024;
    for (int i = (int)threadIdx.x; i < 1024; i += 256) {
        const double nd = (double)(i + 1);
        slog[i] = (float)log(nd);            // correctly-rounded fl32(log n)
        srsq[i] = (float)(1.0 / sqrt(nd));
    }
    __syncthreads();

    const int gid = zblock * 256 + (int)threadIdx.x;
    if (gid >= n) return;

    const float t  = tin[gid];
    const float th = __fmul_rn(t, 0.5f);
    const float logt = (float)log((double)t);
    float theta = __fsub_rn(__fsub_rn(__fmul_rn(th, __fsub_rn(logt, 1.8378770664093453f)), th),
                            0.39269908169872414f);
    theta = __fadd_rn(theta, __fdiv_rn(1.0f, __fmul_rn(48.0f, t)));

    int nt = (int)sqrtf(__fdiv_rn(t, 6.283185307179586f));
    nt = min(max(nt, 10), 1024);

    float acc = 0.0f;
    for (int i = 0; i < nt; ++i) {
        const float p = __fsub_rn(__fmul_rn(t, slog[i]), theta);
        const double rev = (double)p * INV_2PI_D;
        const double fr  = rev - rint(rev);            // |fr| <= 0.5 revolutions
        const float  c   = __builtin_amdgcn_cosf((float)fr);
        acc = __fmaf_rn(srsq[i], c, acc);
    }
    zout[gid] = __fmul_rn(2.0f, acc);
}

__global__ __launch_bounds__(256, 4) void fused_kernel(
    const float* __restrict__ xre, const float* __restrict__ xim,
    const float* __restrict__ tin,
    float* __restrict__ yre, float* __restrict__ yim, float* __restrict__ zout,
    int z_blocks, int nrows, int nz)
{
    __shared__ float zbuf[2048];     // 8 KB: Z table only; FFT uses no LDS

    const int b = (int)blockIdx.x;
    if (b < z_blocks) {
        z_eval(tin, zout, b, nz, zbuf);
    } else {
        const int wid = (int)(threadIdx.x >> 6);
        const int row0 = ((b - z_blocks) << 4) + (wid << 2);   // 16 rows/block
        if (row0 + 3 < nrows)
            fft_wave(xre, xim, yre, yim, row0);
    }
}

extern "C" void kernel_launch(void* const* d_in, const int* in_sizes, int n_in,
                              void* d_out, int out_size, void* d_ws, size_t ws_size,
                              hipStream_t stream)
{
    const float* xre = (const float*)d_in[0];
    const float* xim = (const float*)d_in[1];
    const float* t   = (const float*)d_in[2];

    const size_t nfft = (size_t)in_sizes[0];          // 16384*1024
    const int nrows = (int)(nfft >> 10);              // 16384
    const int nz    = in_sizes[2];                    // 262144

    float* yre = (float*)d_out;
    float* yim = yre + nfft;
    float* z   = yre + 2 * nfft;

    const int f_blocks = (nrows + 15) >> 4;           // 16 rows per block
    const int z_blocks = (nz + 255) >> 8;
    fused_kernel<<<z_blocks + f_blocks, 256, 0, stream>>>(
        xre, xim, t, yre, yim, z, z_blocks, nrows, nz);
}

// Round 13
// 54.570 us; speedup vs baseline: 1.2721x; 1.2721x over previous
//
#include <hip/hip_runtime.h>
#include <math.h>

#define INV_2PI_D 0.15915494309189535

// Cross-lane LDS transpose fence. The waitcnt orders the HW; the "memory"
// clobber stops the compiler from reordering the write-pass and read-pass
// (cross-lane dependence is invisible in per-thread SIMT semantics).
#define LDSYNC() asm volatile("s_waitcnt lgkmcnt(0)" ::: "memory")

// pad: a = e + e/16. All four transpose phases are <=2-way banked (free).
__device__ __forceinline__ int pad(int e) { return e + (e >> 4); }

__device__ __forceinline__ void bfly(float& ar, float& ai, float& br, float& bi,
                                     float wr, float wi) {
    const float tr = wr * br - wi * bi;
    const float ti = wr * bi + wi * br;
    br = ar - tr; bi = ai - ti;
    ar = ar + tr; ai = ai + ti;
}

// w = exp(2*pi*i * rev): hardware v_sin/v_cos take REVOLUTIONS.
// Twiddle revs are -k/2^m -- exactly representable, no range reduction.
__device__ __forceinline__ void wrev(float rev, float& c, float& s) {
    s = __builtin_amdgcn_sinf(rev);
    c = __builtin_amdgcn_cosf(rev);
}

__device__ __forceinline__ void fft_row(
    const float* __restrict__ xre, const float* __restrict__ xim,
    float* __restrict__ yre, float* __restrict__ yim,
    float* __restrict__ s,              // 1088 floats, private to this wave
    int row)
{
    const int lane = (int)(threadIdx.x & 63u);
    const size_t base = (size_t)row << 10;

    float re[16], im[16];

    // ---- bit-reversed loads: for fixed r, rev6(lane) permutes one 256B
    // segment -> fully coalesced despite being "scattered".
    const int rev6l = (int)(__brev((unsigned)lane) >> 26);
    const int REV4[16] = {0,8,4,12,2,10,6,14,1,9,5,13,3,11,7,15};
    const float* xr = xre + base + rev6l;
    const float* xi = xim + base + rev6l;
#pragma unroll
    for (int r = 0; r < 16; ++r) {
        re[r] = xr[REV4[r] << 6];
        im[r] = xi[REV4[r] << 6];
    }

    const int lo = lane & 15;
    const int hi = (lane >> 4) << 8;
    const float lof = (float)lo;

    // ---- L3-stage twiddles, hoisted here to overlap global-load latency.
    float c8a[8], s8a[8];              // s=128: k = 16m + lo
#pragma unroll
    for (int m = 0; m < 8; ++m)
        wrev(-(16.0f * (float)m + lof) * (1.0f / 256.0f), c8a[m], s8a[m]);
    float c4a[4], s4a[4];              // s=64
#pragma unroll
    for (int m = 0; m < 4; ++m)
        wrev(-(16.0f * (float)m + lof) * (1.0f / 128.0f), c4a[m], s4a[m]);
    float c2a[2], s2a[2];              // s=32
#pragma unroll
    for (int m = 0; m < 2; ++m)
        wrev(-(16.0f * (float)m + lof) * (1.0f / 64.0f), c2a[m], s2a[m]);
    float c1a, s1a;                    // s=16
    wrev(-lof * (1.0f / 32.0f), c1a, s1a);

    // ---- L1 stages s=1,2,4,8 (reg-local), exact constant twiddles
    const float W8R[8] = {1.f, 0.9238795325112867f, 0.7071067811865476f,
                          0.3826834323650898f, 0.f, -0.3826834323650898f,
                          -0.7071067811865476f, -0.9238795325112867f};
    const float W8I[8] = {0.f, -0.3826834323650898f, -0.7071067811865476f,
                          -0.9238795325112867f, -1.f, -0.9238795325112867f,
                          -0.7071067811865476f, -0.3826834323650898f};
#pragma unroll
    for (int st = 0; st < 4; ++st) {
        const int S = 1 << st;
#pragma unroll
        for (int rl = 0; rl < 16; ++rl) {
            if (rl & S) continue;
            const int k8 = (rl & (S - 1)) * (8 >> st);
            bfly(re[rl], im[rl], re[rl | S], im[rl | S], W8R[k8], W8I[k8]);
        }
    }

    // ---- T1: L1 (e=lane*16+r) -> L3 (e=(lane>>4)*256+r*16+(lane&15))
#pragma unroll
    for (int r = 0; r < 16; ++r) s[pad(lane * 16 + r)] = re[r];
    LDSYNC();
#pragma unroll
    for (int r = 0; r < 16; ++r) re[r] = s[pad(hi + (r << 4) + lo)];
    LDSYNC();
#pragma unroll
    for (int r = 0; r < 16; ++r) s[pad(lane * 16 + r)] = im[r];
    LDSYNC();
#pragma unroll
    for (int r = 0; r < 16; ++r) im[r] = s[pad(hi + (r << 4) + lo)];
    LDSYNC();

    // ---- L3 stages s=16,32,64,128 (twiddles already in registers)
#pragma unroll
    for (int rl = 0; rl < 16; ++rl) if (!(rl & 1))
        bfly(re[rl], im[rl], re[rl|1], im[rl|1], c1a, s1a);
#pragma unroll
    for (int rl = 0; rl < 16; ++rl) if (!(rl & 2))
        bfly(re[rl], im[rl], re[rl|2], im[rl|2], c2a[rl & 1], s2a[rl & 1]);
#pragma unroll
    for (int rl = 0; rl < 16; ++rl) if (!(rl & 4))
        bfly(re[rl], im[rl], re[rl|4], im[rl|4], c4a[rl & 3], s4a[rl & 3]);
#pragma unroll
    for (int rl = 0; rl < 16; ++rl) if (!(rl & 8))
        bfly(re[rl], im[rl], re[rl|8], im[rl|8], c8a[rl & 7], s8a[rl & 7]);

    // ---- L2-stage twiddles, generated before T2 so they overlap DS waits.
    const float lf = (float)lane;
    float cz8[8], sz8[8];              // s=512: k = 64m + lane
#pragma unroll
    for (int m = 0; m < 8; ++m)
        wrev(-(64.0f * (float)m + lf) * (1.0f / 1024.0f), cz8[m], sz8[m]);
    float cz4[4], sz4[4];              // s=256
#pragma unroll
    for (int m = 0; m < 4; ++m)
        wrev(-(64.0f * (float)m + lf) * (1.0f / 512.0f), cz4[m], sz4[m]);

    // ---- T2: L3 -> L2 (e=r*64+lane), split passes
#pragma unroll
    for (int r = 0; r < 16; ++r) s[pad(hi + (r << 4) + lo)] = re[r];
    LDSYNC();
#pragma unroll
    for (int r = 0; r < 16; ++r) re[r] = s[pad((r << 6) + lane)];
    LDSYNC();
#pragma unroll
    for (int r = 0; r < 16; ++r) s[pad(hi + (r << 4) + lo)] = im[r];
    LDSYNC();
#pragma unroll
    for (int r = 0; r < 16; ++r) im[r] = s[pad((r << 6) + lane)];
    LDSYNC();

    // ---- L2 stages s=256,512
#pragma unroll
    for (int rl = 0; rl < 16; ++rl) if (!(rl & 4))
        bfly(re[rl], im[rl], re[rl|4], im[rl|4], cz4[rl & 3], sz4[rl & 3]);
#pragma unroll
    for (int rl = 0; rl < 16; ++rl) if (!(rl & 8))
        bfly(re[rl], im[rl], re[rl|8], im[rl|8], cz8[rl & 7], sz8[rl & 7]);

    // ---- coalesced stores (fixed r -> one contiguous 256B segment)
    float* yr = yre + base + lane;
    float* yi = yim + base + lane;
#pragma unroll
    for (int r = 0; r < 16; ++r) {
        yr[r << 6] = re[r];
        yi[r << 6] = im[r];
    }
}

// Z: table built in-block (4 f64 log/sqrt per thread, trivial), then the
// float32-semantics phase/cos loop (matches reference rounding).
__device__ void z_eval(const float* __restrict__ tin, float* __restrict__ zout,
                       int zblock, int n, float* __restrict__ buf)
{
    float* slog = buf;
    float* srsq = buf + 1024;
    for (int i = (int)threadIdx.x; i < 1024; i += 256) {
        const double nd = (double)(i + 1);
        slog[i] = (float)log(nd);            // correctly-rounded fl32(log n)
        srsq[i] = (float)(1.0 / sqrt(nd));
    }
    __syncthreads();

    const int gid = zblock * 256 + (int)threadIdx.x;
    if (gid >= n) return;

    const float t  = tin[gid];
    const float th = __fmul_rn(t, 0.5f);
    const float logt = (float)log((double)t);
    float theta = __fsub_rn(__fsub_rn(__fmul_rn(th, __fsub_rn(logt, 1.8378770664093453f)), th),
                            0.39269908169872414f);
    theta = __fadd_rn(theta, __fdiv_rn(1.0f, __fmul_rn(48.0f, t)));

    int nt = (int)sqrtf(__fdiv_rn(t, 6.283185307179586f));
    nt = min(max(nt, 10), 1024);

    float acc = 0.0f;
    for (int i = 0; i < nt; ++i) {
        const float p = __fsub_rn(__fmul_rn(t, slog[i]), theta);
        const double rev = (double)p * INV_2PI_D;
        const double fr  = rev - rint(rev);            // |fr| <= 0.5 revolutions
        const float  c   = __builtin_amdgcn_cosf((float)fr);
        acc = __fmaf_rn(srsq[i], c, acc);
    }
    zout[gid] = __fmul_rn(2.0f, acc);
}

// Block-role interleave: every 3rd block is a Z block (while Z blocks last),
// so each CU concurrently holds FFT (memory+VALU) and Z (pure VALU) work.
// Z compute fills FFT stall cycles instead of running as a serial prefix.
__global__ __launch_bounds__(256, 6) void fused_kernel(
    const float* __restrict__ xre, const float* __restrict__ xim,
    const float* __restrict__ tin,
    float* __restrict__ yre, float* __restrict__ yim, float* __restrict__ zout,
    int z_blocks, int nrows, int nz)
{
    __shared__ float s[4][1088];     // 17408 B/block -> 6 blocks/CU

    const int b = (int)blockIdx.x;
    const int zi = b / 3;
    const bool isZ = ((b % 3) == 2) && (zi < z_blocks);

    if (isZ) {
        z_eval(tin, zout, zi, nz, &s[0][0]);
    } else {
        // # of Z blocks with id < b:
        const int zbefore = min((b + 1) / 3, z_blocks);
        const int fi = b - zbefore;
        const int wid = (int)(threadIdx.x >> 6);
        const int row = (fi << 2) | wid;
        if (row < nrows)
            fft_row(xre, xim, yre, yim, s[wid], row);
    }
}

extern "C" void kernel_launch(void* const* d_in, const int* in_sizes, int n_in,
                              void* d_out, int out_size, void* d_ws, size_t ws_size,
                              hipStream_t stream)
{
    const float* xre = (const float*)d_in[0];
    const float* xim = (const float*)d_in[1];
    const float* t   = (const float*)d_in[2];

    const size_t nfft = (size_t)in_sizes[0];          // 16384*1024
    const int nrows = (int)(nfft >> 10);              // 16384
    const int nz    = in_sizes[2];                    // 262144

    float* yre = (float*)d_out;
    float* yim = yre + nfft;
    float* z   = yre + 2 * nfft;

    const int f_blocks = (nrows + 3) >> 2;            // 4 rows per block
    const int z_blocks = (nz + 255) >> 8;
    fused_kernel<<<f_blocks + z_blocks, 256, 0, stream>>>(
        xre, xim, t, yre, yim, z, z_blocks, nrows, nz);
}